// Round 1
// baseline (863.863 us; speedup 1.0000x reference)
//
#include <hip/hip_runtime.h>
#include <hip/hip_bf16.h>
#include <math.h>

#define NTOK   8192
#define HIDDEN 2048
#define FFN_   2048
#define NEXP   8
#define TOPK   2
#define MTOT   (NTOK*TOPK)   // 16384 scattered rows
#define CAP    (MTOT/NEXP)   // 2048 rows per expert

typedef __bf16 bf16_t;
typedef __attribute__((ext_vector_type(8))) __bf16 bf16x8;
typedef __attribute__((ext_vector_type(4))) float  f32x4;

// ---- async global->LDS, 16B per lane (wave-uniform LDS base + lane*16) ----
__device__ __forceinline__ void async16(const bf16_t* g, bf16_t* l) {
    __builtin_amdgcn_global_load_lds(
        (const __attribute__((address_space(1))) void*)g,
        (__attribute__((address_space(3))) void*)l,
        16, 0, 0);
}

// inv[scatter[i]] = i  (scatter is a permutation of [0, MTOT))
__global__ void k_build_inv(const int* __restrict__ scat, int* __restrict__ inv) {
    int i = blockIdx.x * 256 + threadIdx.x;
    inv[scat[i]] = i;
}

// x_bf16[m, :] = bf16(inputs[inv[m]/TOPK, :])   (gather + cast, 8 elems/thread)
__global__ void k_cast_x(const float* __restrict__ x, const int* __restrict__ inv,
                         bf16_t* __restrict__ xb) {
    int idx = blockIdx.x * 256 + threadIdx.x;       // [0, MTOT*HIDDEN/8)
    int m = idx >> 8;                               // HIDDEN/8 = 256 threads per row
    int j = (idx & 255) << 3;
    int src = inv[m] / TOPK;
    const float4* p = (const float4*)(x + (size_t)src * HIDDEN + j);
    float4 a = p[0], b = p[1];
    bf16x8 o;
    o[0] = (bf16_t)a.x; o[1] = (bf16_t)a.y; o[2] = (bf16_t)a.z; o[3] = (bf16_t)a.w;
    o[4] = (bf16_t)b.x; o[5] = (bf16_t)b.y; o[6] = (bf16_t)b.z; o[7] = (bf16_t)b.w;
    *(bf16x8*)(xb + (size_t)m * HIDDEN + j) = o;
}

// plain fp32 -> bf16 cast, 8 elems/thread
__global__ void k_cast(const float* __restrict__ src, bf16_t* __restrict__ dst) {
    int idx = blockIdx.x * 256 + threadIdx.x;
    const float4* p = (const float4*)(src + (size_t)idx * 8);
    float4 a = p[0], b = p[1];
    bf16x8 o;
    o[0] = (bf16_t)a.x; o[1] = (bf16_t)a.y; o[2] = (bf16_t)a.z; o[3] = (bf16_t)a.w;
    o[4] = (bf16_t)b.x; o[5] = (bf16_t)b.y; o[6] = (bf16_t)b.z; o[7] = (bf16_t)b.w;
    *(bf16x8*)(dst + (size_t)idx * 8) = o;
}

// C = A * B^T per expert. A: [NEXP, CAP, 2048] row-major, B: [NEXP, 2048, 2048]
// row-major (N x K). 128x128 tile / block, 256 threads = 4 waves (2x2 of 64x64),
// BK=32, one 16x16x32 bf16 MFMA per subtile per K-step.
// EPI=0: exact GELU then bf16 store to Hout ([MTOT, FFN_] row-major).
// EPI=1: atomicAdd fp32 into Out[inv[row]/TOPK, col]  (topk combine fused).
template <int EPI>
__global__ __launch_bounds__(256)
void k_gemm(const bf16_t* __restrict__ A, const bf16_t* __restrict__ B,
            bf16_t* __restrict__ Hout, float* __restrict__ Out,
            const int* __restrict__ inv) {
    const int K = 2048, N = 2048;
    int bid = blockIdx.x;
    int e  = bid >> 8;                 // 16x16 = 256 tiles per expert
    int t  = bid & 255;
    int row0 = (t >> 4) * 128;
    int col0 = (t & 15) * 128;
    const bf16_t* Ae = A + (size_t)e * CAP * K;
    const bf16_t* Be = B + (size_t)e * N * K;

    __shared__ __align__(16) bf16_t As[128 * 32];
    __shared__ __align__(16) bf16_t Bs[128 * 32];

    int tid  = threadIdx.x;
    int lane = tid & 63;
    int wid  = tid >> 6;
    int wm = (wid >> 1) * 64;          // wave row offset in tile
    int wn = (wid & 1) * 64;           // wave col offset in tile

    f32x4 acc[4][4] = {};

    // staging: chunk c covers rows [c*64, c*64+64); thread t -> row tid/4,
    // k-seg (tid&3)*8; LDS byte offset = (c*256+tid)*16 (lane-contiguous).
    int sr = tid >> 2;
    int sk = (tid & 3) << 3;

    int lm = lane & 15;                // fragment row/col within 16
    int lk = (lane >> 4) << 3;         // fragment k offset: 0/8/16/24

    for (int k0 = 0; k0 < K; k0 += 32) {
        const bf16_t* ga = Ae + (size_t)(row0 + sr) * K + k0 + sk;
        const bf16_t* gb = Be + (size_t)(col0 + sr) * K + k0 + sk;
        async16(ga,            &As[(size_t)tid * 8]);
        async16(ga + 64 * K,   &As[(size_t)(256 + tid) * 8]);
        async16(gb,            &Bs[(size_t)tid * 8]);
        async16(gb + 64 * K,   &Bs[(size_t)(256 + tid) * 8]);
        __syncthreads();

        bf16x8 af[4], bfr[4];
        #pragma unroll
        for (int i = 0; i < 4; i++) {
            af[i]  = *(const bf16x8*)&As[(wm + i * 16 + lm) * 32 + lk];
            bfr[i] = *(const bf16x8*)&Bs[(wn + i * 16 + lm) * 32 + lk];
        }
        #pragma unroll
        for (int i = 0; i < 4; i++)
            #pragma unroll
            for (int j = 0; j < 4; j++)
                acc[i][j] = __builtin_amdgcn_mfma_f32_16x16x32_bf16(
                    af[i], bfr[j], acc[i][j], 0, 0, 0);
        __syncthreads();
    }

    // epilogue: C element (row, col): row = (lane>>4)*4 + reg, col = lane&15
    int rbase = (lane >> 4) * 4;
    #pragma unroll
    for (int i = 0; i < 4; i++) {
        #pragma unroll
        for (int j = 0; j < 4; j++) {
            #pragma unroll
            for (int r = 0; r < 4; r++) {
                float v = acc[i][j][r];
                int row = row0 + wm + i * 16 + rbase + r;
                int col = col0 + wn + j * 16 + lm;
                if (EPI == 0) {
                    v = 0.5f * v * (1.0f + erff(v * 0.70710678118f));
                    Hout[((size_t)e * CAP + row) * N + col] = (bf16_t)v;
                } else {
                    int gm  = e * CAP + row;
                    int tok = inv[gm] / TOPK;
                    atomicAdd(&Out[(size_t)tok * HIDDEN + col], v);
                }
            }
        }
    }
}

extern "C" void kernel_launch(void* const* d_in, const int* in_sizes, int n_in,
                              void* d_out, int out_size, void* d_ws, size_t ws_size,
                              hipStream_t stream) {
    const float* x    = (const float*)d_in[0];
    const float* w1   = (const float*)d_in[1];
    const float* w2   = (const float*)d_in[2];
    const int*   scat = (const int*)d_in[3];
    float* out = (float*)d_out;

    char* ws = (char*)d_ws;
    size_t off = 0;
    int*    inv = (int*)(ws + off);     off += 65536;                         // MTOT*4, padded
    bf16_t* xb  = (bf16_t*)(ws + off);  off += (size_t)MTOT * HIDDEN * 2;     // 64 MB
    bf16_t* w1b = (bf16_t*)(ws + off);  off += (size_t)NEXP * FFN_ * HIDDEN * 2;
    bf16_t* w2b = (bf16_t*)(ws + off);  off += (size_t)NEXP * HIDDEN * FFN_ * 2;
    bf16_t* hb  = (bf16_t*)(ws + off);  off += (size_t)MTOT * FFN_ * 2;

    hipMemsetAsync(d_out, 0, (size_t)out_size * sizeof(float), stream);

    k_build_inv<<<MTOT / 256, 256, 0, stream>>>(scat, inv);
    k_cast_x<<<MTOT * (HIDDEN / 8) / 256, 256, 0, stream>>>(x, inv, xb);
    int n8blocks = NEXP * FFN_ * (HIDDEN / 8) / 256;   // 16384 blocks
    k_cast<<<n8blocks, 256, 0, stream>>>(w1, w1b);
    k_cast<<<n8blocks, 256, 0, stream>>>(w2, w2b);

    k_gemm<0><<<NEXP * 256, 256, 0, stream>>>(xb, w1b, hb, nullptr, nullptr);
    k_gemm<1><<<NEXP * 256, 256, 0, stream>>>(hb, w2b, nullptr, out, inv);
}